// Round 1
// baseline (201.713 us; speedup 1.0000x reference)
//
#include <hip/hip_runtime.h>
#include <hip/hip_bf16.h>

#define HW   3136   // 56*56
#define WID  56
#define CIN  256
#define NH   8
#define HD   32
#define KK   49
#define MAPF (2 * 256 * HW)   // floats per map (B * nH*hd * HW)

// ---------------------------------------------------------------------------
// Kernel A: fused QKV projection.  Per batch b:
//   C[m][p] = sum_c W3[m][c] * x[b][c][p],  m in [0,768), p in [0,3136)
// m = proj*256 + n*32 + d; output written planar: map[proj][(b*256 + n*32+d)*HW + p]
// Tiling: 64 m x 64 p per block, BK=16, 256 threads, 4x4 register tile.
// ---------------------------------------------------------------------------
__global__ __launch_bounds__(256) void proj_kernel(
    const float* __restrict__ x,
    const float* __restrict__ Wk,
    const float* __restrict__ Wq,
    const float* __restrict__ Wv,
    float* __restrict__ ws)
{
    __shared__ float Xs[16][64];
    __shared__ float Wsh[64][17];

    const int bx   = blockIdx.x;        // 0..97 : batch * pixel-block
    const int b    = bx / 49;
    const int p0   = (bx % 49) * 64;
    const int mblk = blockIdx.y;        // 0..11
    const int m0   = mblk * 64;
    const int proj = mblk >> 2;         // 0:k 1:q 2:v  (4 mblks per 256-row W)
    const int mbase = m0 & 255;

    const float* Wp = (proj == 0) ? Wk : (proj == 1 ? Wq : Wv);
    const float* Xb = x + (size_t)b * CIN * HW;

    const int t  = threadIdx.x;
    const int tx = t & 15;              // pixel quad -> pixels p0 + tx*4 .. +3
    const int ty = t >> 4;              // m quad     -> m0 + ty*4 .. +3

    const int lpx = t & 63;             // X staging: pixel
    const int lcs = t >> 6;             // X staging: c row base (0..3)
    const int wcs = t & 15;             // W staging: c
    const int wms = t >> 4;             // W staging: m row base (0..15)

    float acc[4][4] = {};

    for (int c0 = 0; c0 < CIN; c0 += 16) {
        #pragma unroll
        for (int r = 0; r < 4; ++r) {
            int cs = lcs + r * 4;
            Xs[cs][lpx] = Xb[(size_t)(c0 + cs) * HW + p0 + lpx];
        }
        #pragma unroll
        for (int r = 0; r < 4; ++r) {
            int ms = wms + r * 16;
            Wsh[ms][wcs] = Wp[(size_t)(mbase + ms) * CIN + c0 + wcs];
        }
        __syncthreads();
        #pragma unroll
        for (int cc = 0; cc < 16; ++cc) {
            float4 xv = *(const float4*)&Xs[cc][tx * 4];
            #pragma unroll
            for (int i = 0; i < 4; ++i) {
                float w = Wsh[ty * 4 + i][cc];
                acc[i][0] += w * xv.x;
                acc[i][1] += w * xv.y;
                acc[i][2] += w * xv.z;
                acc[i][3] += w * xv.w;
            }
        }
        __syncthreads();
    }

    float* mapb = ws + (size_t)proj * MAPF;
    #pragma unroll
    for (int i = 0; i < 4; ++i) {
        int rloc = mbase + ty * 4 + i;
        float4 v = make_float4(acc[i][0], acc[i][1], acc[i][2], acc[i][3]);
        *(float4*)&mapb[(size_t)(b * 256 + rloc) * HW + p0 + tx * 4] = v;
    }
}

// ---------------------------------------------------------------------------
// Kernel B: local attention.  One thread per output pixel (b, n, pix).
// Planar maps -> every q/v load is coalesced across the wave.
// OOB window cells: q contributes 0 but rel bias still enters the softmax;
// v contributes 0 to the output.
// ---------------------------------------------------------------------------
__global__ __launch_bounds__(64) void attn_kernel(
    const float* __restrict__ ws,
    const float* __restrict__ rel_h,
    const float* __restrict__ rel_w,
    float* __restrict__ out)
{
    const int pix = blockIdx.x * 64 + threadIdx.x;   // 0..3135 (49*64 exact)
    const int n   = blockIdx.y;
    const int b   = blockIdx.z;

    const int y = pix / WID;
    const int x = pix - y * WID;

    const size_t bn = (size_t)(b * 256 + n * HD) * HW;  // d=0 plane offset
    const float* kmap = ws;
    const float* qmap = ws + (size_t)1 * MAPF;
    const float* vmap = ws + (size_t)2 * MAPF;

    float kc[HD];
    #pragma unroll
    for (int d = 0; d < HD; ++d)
        kc[d] = kmap[bn + (size_t)d * HW + pix];

    // rel bias: logit(i,j) += rh[i] + rw[j]
    float rh[7], rw[7];
    #pragma unroll
    for (int i = 0; i < 7; ++i) {
        float a = 0.f, c = 0.f;
        #pragma unroll
        for (int dd = 0; dd < 16; ++dd) {
            a += rel_h[(n * 7 + i) * 16 + dd] * kc[dd];
            c += rel_w[(n * 7 + i) * 16 + dd] * kc[16 + dd];
        }
        rh[i] = a; rw[i] = c;
    }

    float logit[KK];
    #pragma unroll
    for (int i = 0; i < 7; ++i) {
        #pragma unroll
        for (int j = 0; j < 7; ++j) {
            int y2 = y + i - 3, x2 = x + j - 3;
            bool valid = ((unsigned)y2 < 56u) && ((unsigned)x2 < 56u);
            int wp = valid ? (y2 * WID + x2) : pix;   // clamp to a safe addr
            float dot = 0.f;
            #pragma unroll
            for (int d = 0; d < HD; ++d)
                dot += kc[d] * qmap[bn + (size_t)d * HW + wp];
            logit[i * 7 + j] = rh[i] + rw[j] + (valid ? dot : 0.f);
        }
    }

    float m = logit[0];
    #pragma unroll
    for (int k = 1; k < KK; ++k) m = fmaxf(m, logit[k]);
    float s = 0.f;
    #pragma unroll
    for (int k = 0; k < KK; ++k) { logit[k] = __expf(logit[k] - m); s += logit[k]; }
    const float inv = 1.f / s;

    float o[HD] = {};
    #pragma unroll
    for (int i = 0; i < 7; ++i) {
        #pragma unroll
        for (int j = 0; j < 7; ++j) {
            int y2 = y + i - 3, x2 = x + j - 3;
            bool valid = ((unsigned)y2 < 56u) && ((unsigned)x2 < 56u);
            int wp = valid ? (y2 * WID + x2) : pix;
            float a = valid ? logit[i * 7 + j] * inv : 0.f;
            #pragma unroll
            for (int d = 0; d < HD; ++d)
                o[d] += a * vmap[bn + (size_t)d * HW + wp];
        }
    }

    #pragma unroll
    for (int d = 0; d < HD; ++d)
        out[bn + (size_t)d * HW + pix] = o[d];
}

extern "C" void kernel_launch(void* const* d_in, const int* in_sizes, int n_in,
                              void* d_out, int out_size, void* d_ws, size_t ws_size,
                              hipStream_t stream) {
    const float* x     = (const float*)d_in[0];
    const float* Wk    = (const float*)d_in[1];
    const float* Wq    = (const float*)d_in[2];
    const float* Wv    = (const float*)d_in[3];
    const float* rel_h = (const float*)d_in[4];
    const float* rel_w = (const float*)d_in[5];
    float* out = (float*)d_out;
    float* ws  = (float*)d_ws;

    hipLaunchKernelGGL(proj_kernel, dim3(98, 12), dim3(256), 0, stream,
                       x, Wk, Wq, Wv, ws);
    hipLaunchKernelGGL(attn_kernel, dim3(49, NH, 2), dim3(64), 0, stream,
                       ws, rel_h, rel_w, out);
}

// Round 2
// 111.043 us; speedup vs baseline: 1.8165x; 1.8165x over previous
//
#include <hip/hip_runtime.h>
#include <hip/hip_bf16.h>

#define HW   3136   // 56*56
#define WID  56
#define CIN  256
#define NH   8
#define HD   32
#define KK   49
#define MAPF (2 * 256 * HW)   // floats per map (B * nH*hd * HW)
#define NW   8                // waves per attn block

// ---------------------------------------------------------------------------
// Kernel A: fused QKV projection.  Per batch b:
//   C[m][p] = sum_c W3[m][c] * x[b][c][p],  m in [0,768), p in [0,3136)
// Output planar: map[proj][(b*256 + n*32+d)*HW + p]
// ---------------------------------------------------------------------------
__global__ __launch_bounds__(256) void proj_kernel(
    const float* __restrict__ x,
    const float* __restrict__ Wk,
    const float* __restrict__ Wq,
    const float* __restrict__ Wv,
    float* __restrict__ ws)
{
    __shared__ float Xs[16][64];
    __shared__ float Wsh[64][17];

    const int bx   = blockIdx.x;        // 0..97 : batch * pixel-block
    const int b    = bx / 49;
    const int p0   = (bx % 49) * 64;
    const int mblk = blockIdx.y;        // 0..11
    const int m0   = mblk * 64;
    const int proj = mblk >> 2;         // 0:k 1:q 2:v
    const int mbase = m0 & 255;

    const float* Wp = (proj == 0) ? Wk : (proj == 1 ? Wq : Wv);
    const float* Xb = x + (size_t)b * CIN * HW;

    const int t  = threadIdx.x;
    const int tx = t & 15;
    const int ty = t >> 4;

    const int lpx = t & 63;
    const int lcs = t >> 6;
    const int wcs = t & 15;
    const int wms = t >> 4;

    float acc[4][4] = {};

    for (int c0 = 0; c0 < CIN; c0 += 16) {
        #pragma unroll
        for (int r = 0; r < 4; ++r) {
            int cs = lcs + r * 4;
            Xs[cs][lpx] = Xb[(size_t)(c0 + cs) * HW + p0 + lpx];
        }
        #pragma unroll
        for (int r = 0; r < 4; ++r) {
            int ms = wms + r * 16;
            Wsh[ms][wcs] = Wp[(size_t)(mbase + ms) * CIN + c0 + wcs];
        }
        __syncthreads();
        #pragma unroll
        for (int cc = 0; cc < 16; ++cc) {
            float4 xv = *(const float4*)&Xs[cc][tx * 4];
            #pragma unroll
            for (int i = 0; i < 4; ++i) {
                float w = Wsh[ty * 4 + i][cc];
                acc[i][0] += w * xv.x;
                acc[i][1] += w * xv.y;
                acc[i][2] += w * xv.z;
                acc[i][3] += w * xv.w;
            }
        }
        __syncthreads();
    }

    float* mapb = ws + (size_t)proj * MAPF;
    #pragma unroll
    for (int i = 0; i < 4; ++i) {
        int rloc = mbase + ty * 4 + i;
        float4 v = make_float4(acc[i][0], acc[i][1], acc[i][2], acc[i][3]);
        *(float4*)&mapb[(size_t)(b * 256 + rloc) * HW + p0 + tx * 4] = v;
    }
}

// ---------------------------------------------------------------------------
// Kernel B: local attention, 8 waves per block.
//   - block = (b, n, 64-pixel tile); lane = pixel
//   - QK phase: cells k = w mod 8 per wave, logits kept in registers
//   - softmax: partial max/sum per wave -> LDS tree reduce
//   - PV phase: wave w owns d = w*4 .. w*4+3; attn weights from LDS
// XCD-bijective swizzle over the 784-block grid (784 = 8*98).
// ---------------------------------------------------------------------------
__global__ __launch_bounds__(512) void attn_kernel(
    const float* __restrict__ ws,
    const float* __restrict__ rel_h,
    const float* __restrict__ rel_w,
    float* __restrict__ out)
{
    __shared__ float Llds[KK][64];     // exp(l - m) per (cell, pixel)
    __shared__ float mpart[NW][64];
    __shared__ float spart[NW][64];

    const int bid = blockIdx.x;
    const int swz = (bid & 7) * 98 + (bid >> 3);
    const int b    = swz / 392;
    const int rem  = swz - b * 392;
    const int n    = rem / 49;
    const int pblk = rem - n * 49;

    const int t    = threadIdx.x;
    const int lane = t & 63;
    const int w    = t >> 6;
    const int pix  = pblk * 64 + lane;
    const int y    = pix / WID;
    const int x    = pix - y * WID;

    const size_t bn = (size_t)(b * 256 + n * HD) * HW;
    const float* kmap = ws;
    const float* qmap = ws + (size_t)MAPF;
    const float* vmap = ws + (size_t)(2 * MAPF);

    // center key vector (needed by every wave for its dot products)
    float kc[HD];
    #pragma unroll
    for (int d = 0; d < HD; ++d)
        kc[d] = kmap[bn + (size_t)d * HW + pix];

    // rel bias: logit(i,j) += rh[i] + rw[j]   (redundant per wave, cheap)
    float rh[7], rw[7];
    #pragma unroll
    for (int i = 0; i < 7; ++i) {
        float a = 0.f, c = 0.f;
        #pragma unroll
        for (int dd = 0; dd < 16; ++dd) {
            a += rel_h[(n * 7 + i) * 16 + dd] * kc[dd];
            c += rel_w[(n * 7 + i) * 16 + dd] * kc[16 + dd];
        }
        rh[i] = a; rw[i] = c;
    }

    // Phase 1: this wave's cells k = w + 8c.  Static l[] indexing (no scratch).
    float l[7];
    float lm = -1e30f;
    #pragma unroll
    for (int c = 0; c < 7; ++c) {
        const int k = w + c * NW;
        if (k < KK) {                      // uniform per wave (only c==6, w>0 fails)
            int i = k / 7, j = k - i * 7;
            int y2 = y + i - 3, x2 = x + j - 3;
            bool valid = ((unsigned)y2 < 56u) && ((unsigned)x2 < 56u);
            int wp = valid ? y2 * WID + x2 : pix;
            float dot = 0.f;
            #pragma unroll
            for (int d = 0; d < HD; ++d)
                dot += kc[d] * qmap[bn + (size_t)d * HW + wp];
            float lv = rh[i] + rw[j] + (valid ? dot : 0.f);
            l[c] = lv;
            lm = fmaxf(lm, lv);
        } else {
            l[c] = -1e30f;
        }
    }
    mpart[w][lane] = lm;
    __syncthreads();

    float m = mpart[0][lane];
    #pragma unroll
    for (int ww = 1; ww < NW; ++ww) m = fmaxf(m, mpart[ww][lane]);

    float lsum = 0.f;
    #pragma unroll
    for (int c = 0; c < 7; ++c) {
        const int k = w + c * NW;
        if (k < KK) {
            float e = __expf(l[c] - m);
            lsum += e;
            Llds[k][lane] = e;
        }
    }
    spart[w][lane] = lsum;
    __syncthreads();

    float s = spart[0][lane];
    #pragma unroll
    for (int ww = 1; ww < NW; ++ww) s += spart[ww][lane];
    const float inv = 1.f / s;

    // Phase 3: wave w produces output planes d0..d0+3
    const int d0 = w * 4;
    const float* vb = vmap + bn + (size_t)d0 * HW;
    float o[4] = {};
    #pragma unroll
    for (int k = 0; k < KK; ++k) {
        const int i = k / 7, j = k - i * 7;
        int y2 = y + i - 3, x2 = x + j - 3;
        bool valid = ((unsigned)y2 < 56u) && ((unsigned)x2 < 56u);
        int wp = valid ? y2 * WID + x2 : pix;
        float a = valid ? Llds[k][lane] * inv : 0.f;
        #pragma unroll
        for (int dd = 0; dd < 4; ++dd)
            o[dd] += a * vb[(size_t)dd * HW + wp];
    }
    #pragma unroll
    for (int dd = 0; dd < 4; ++dd)
        out[bn + (size_t)(d0 + dd) * HW + pix] = o[dd];
}

extern "C" void kernel_launch(void* const* d_in, const int* in_sizes, int n_in,
                              void* d_out, int out_size, void* d_ws, size_t ws_size,
                              hipStream_t stream) {
    const float* x     = (const float*)d_in[0];
    const float* Wk    = (const float*)d_in[1];
    const float* Wq    = (const float*)d_in[2];
    const float* Wv    = (const float*)d_in[3];
    const float* rel_h = (const float*)d_in[4];
    const float* rel_w = (const float*)d_in[5];
    float* out = (float*)d_out;
    float* ws  = (float*)d_ws;

    hipLaunchKernelGGL(proj_kernel, dim3(98, 12), dim3(256), 0, stream,
                       x, Wk, Wq, Wv, ws);
    hipLaunchKernelGGL(attn_kernel, dim3(784), dim3(512), 0, stream,
                       ws, rel_h, rel_w, out);
}

// Round 3
// 81.730 us; speedup vs baseline: 2.4680x; 1.3587x over previous
//
#include <hip/hip_runtime.h>
#include <hip/hip_bf16.h>

#define HW   3136   // 56*56
#define WID  56
#define CIN  256
#define NH   8
#define HD   32
#define KK   49
#define MAPF (2 * NH * HW * HD)   // floats per map
#define NW   8                    // waves per attn block

#define SROWS 196   // 14*14 staged halo window
#define QSTR  36    // floats per staged q row   (144 B stride: 9 mod 8 = 1 -> spread)
#define VSTR  40    // ushorts per staged v row  (80 B stride:  5 mod 8 = 5 -> spread)

__device__ __forceinline__ unsigned f2bf(float x) {        // RNE f32->bf16 bits
    unsigned u = __float_as_uint(x);
    return (u + 0x7fffu + ((u >> 16) & 1u)) >> 16;
}
__device__ __forceinline__ float bfb2f(unsigned h) { return __uint_as_float(h << 16); }
__device__ __forceinline__ float bf2f_lo(unsigned u) { return __uint_as_float(u << 16); }
__device__ __forceinline__ float bf2f_hi(unsigned u) { return __uint_as_float(u & 0xffff0000u); }

// ---------------------------------------------------------------------------
// Kernel A: fused QKV projection GEMM.  C[m][p] = sum_c W[m][c] * x[b][c][p].
// Output layout: map[proj][((b*NH + n)*HW + pix)*HD + d]   (d contiguous)
// ---------------------------------------------------------------------------
__global__ __launch_bounds__(256) void proj_kernel(
    const float* __restrict__ x,
    const float* __restrict__ Wk,
    const float* __restrict__ Wq,
    const float* __restrict__ Wv,
    float* __restrict__ ws)
{
    __shared__ float Xs[16][64];
    __shared__ float Wsh[64][17];

    const int bx   = blockIdx.x;        // 0..97 : batch * pixel-block
    const int b    = bx / 49;
    const int p0   = (bx % 49) * 64;
    const int mblk = blockIdx.y;        // 0..11
    const int m0   = mblk * 64;
    const int proj = mblk >> 2;         // 0:k 1:q 2:v
    const int mbase = m0 & 255;

    const float* Wp = (proj == 0) ? Wk : (proj == 1 ? Wq : Wv);
    const float* Xb = x + (size_t)b * CIN * HW;

    const int t  = threadIdx.x;
    const int tx = t & 15;
    const int ty = t >> 4;

    const int lpx = t & 63;
    const int lcs = t >> 6;
    const int wcs = t & 15;
    const int wms = t >> 4;

    float acc[4][4] = {};

    for (int c0 = 0; c0 < CIN; c0 += 16) {
        #pragma unroll
        for (int r = 0; r < 4; ++r) {
            int cs = lcs + r * 4;
            Xs[cs][lpx] = Xb[(size_t)(c0 + cs) * HW + p0 + lpx];
        }
        #pragma unroll
        for (int r = 0; r < 4; ++r) {
            int ms = wms + r * 16;
            Wsh[ms][wcs] = Wp[(size_t)(mbase + ms) * CIN + c0 + wcs];
        }
        __syncthreads();
        #pragma unroll
        for (int cc = 0; cc < 16; ++cc) {
            float4 xv = *(const float4*)&Xs[cc][tx * 4];
            #pragma unroll
            for (int i = 0; i < 4; ++i) {
                float w = Wsh[ty * 4 + i][cc];
                acc[i][0] += w * xv.x;
                acc[i][1] += w * xv.y;
                acc[i][2] += w * xv.z;
                acc[i][3] += w * xv.w;
            }
        }
        __syncthreads();
    }

    float* mapb = ws + (size_t)proj * MAPF;
    const int nloc  = (mbase + ty * 4) >> 5;   // head within this proj
    const int dbase = (mbase + ty * 4) & 31;   // 4 consecutive d
    #pragma unroll
    for (int j = 0; j < 4; ++j) {
        int p = p0 + tx * 4 + j;
        float4 v = make_float4(acc[0][j], acc[1][j], acc[2][j], acc[3][j]);
        *(float4*)&mapb[((size_t)(b * NH + nloc) * HW + p) * HD + dbase] = v;
    }
}

// ---------------------------------------------------------------------------
// Kernel B: local attention.  Block = (b, n, 8x8 pixel tile), 512 threads.
//   - stage 14x14 halo window: q as f32 (stride-36 rows), v as bf16 (stride-40)
//   - OOB slots staged as exact zeros -> no masks in inner loops
//   - rel-bias dots computed once per block into LDS
//   - QK: wave w owns cells k = w+8c; softmax via LDS partials
//   - PV: wave w owns d = 4w..4w+3, attn weights from bf16 Llds
// ---------------------------------------------------------------------------
__global__ __launch_bounds__(512, 4) void attn_kernel(
    const float* __restrict__ ws,
    const float* __restrict__ rel_h,
    const float* __restrict__ rel_w,
    float* __restrict__ out)
{
    __shared__ float          stq[SROWS * QSTR];   // 28224 B
    __shared__ unsigned short stv[SROWS * VSTR];   // 15680 B
    __shared__ unsigned short Llds[KK][64];        //  6272 B
    __shared__ float          rhw[14][64];         //  3584 B
    __shared__ float          mpart[NW][64];       //  2048 B
    __shared__ float          spart[NW][64];       //  2048 B

    const int bid = blockIdx.x;
    const int swz = (bid & 7) * 98 + (bid >> 3);   // XCD-bijective (784 = 8*98)
    const int b    = swz / 392;
    const int rem  = swz - b * 392;
    const int n    = rem / 49;
    const int tile = rem - n * 49;
    const int ty0  = (tile / 7) * 8;
    const int tx0  = (tile % 7) * 8;

    const int t    = threadIdx.x;
    const int lane = t & 63;
    const int w    = t >> 6;
    const int py   = lane >> 3;
    const int px   = lane & 7;
    const int pix  = (ty0 + py) * WID + tx0 + px;

    const float* kmap = ws;
    const float* qmap = ws + (size_t)MAPF;
    const float* vmap = ws + (size_t)(2 * MAPF);
    const size_t mb   = (size_t)(b * NH + n) * HW;   // pixel-record base

    // ---- stage q (f32) ----
    #pragma unroll
    for (int kk = 0; kk < 4; ++kk) {
        int f = t + kk * 512;
        if (f < SROWS * 8) {
            int sp = f >> 3, ch = f & 7;
            int sy = sp / 14, sx = sp - sy * 14;
            int gy = ty0 + sy - 3, gx = tx0 + sx - 3;
            float4 val = make_float4(0.f, 0.f, 0.f, 0.f);
            if ((unsigned)gy < 56u && (unsigned)gx < 56u)
                val = *(const float4*)&qmap[(mb + gy * WID + gx) * HD + ch * 4];
            *(float4*)&stq[sp * QSTR + ch * 4] = val;
        }
    }
    // ---- stage v (bf16) ----
    #pragma unroll
    for (int kk = 0; kk < 4; ++kk) {
        int f = t + kk * 512;
        if (f < SROWS * 8) {
            int sp = f >> 3, ch = f & 7;
            int sy = sp / 14, sx = sp - sy * 14;
            int gy = ty0 + sy - 3, gx = tx0 + sx - 3;
            float4 val = make_float4(0.f, 0.f, 0.f, 0.f);
            if ((unsigned)gy < 56u && (unsigned)gx < 56u)
                val = *(const float4*)&vmap[(mb + gy * WID + gx) * HD + ch * 4];
            unsigned ux = f2bf(val.x) | (f2bf(val.y) << 16);
            unsigned uy = f2bf(val.z) | (f2bf(val.w) << 16);
            *(uint2*)&stv[sp * VSTR + ch * 4] = make_uint2(ux, uy);
        }
    }

    // ---- center key vector (f32, from global; L1-hot after first wave) ----
    float kc[HD];
    #pragma unroll
    for (int c4 = 0; c4 < 8; ++c4) {
        float4 v4 = *(const float4*)&kmap[(mb + pix) * HD + c4 * 4];
        kc[c4 * 4 + 0] = v4.x; kc[c4 * 4 + 1] = v4.y;
        kc[c4 * 4 + 2] = v4.z; kc[c4 * 4 + 3] = v4.w;
    }

    // ---- rel bias dots, once per block (waves 0..6) ----
    if (w < 7) {
        float a = 0.f, c = 0.f;
        #pragma unroll
        for (int dd = 0; dd < 16; ++dd) {
            a += rel_h[(n * 7 + w) * 16 + dd] * kc[dd];
            c += rel_w[(n * 7 + w) * 16 + dd] * kc[16 + dd];
        }
        rhw[w][lane]     = a;
        rhw[7 + w][lane] = c;
    }
    __syncthreads();

    // ---- QK: wave w owns cells k = w + 8c ----
    const int spc = py * 14 + px;
    float l[7];
    float lm = -1e30f;
    #pragma unroll
    for (int c = 0; c < 7; ++c) {
        const int k = w + c * NW;
        if (k < KK) {                       // wave-uniform
            int i = k / 7, j = k - i * 7;
            int sp = spc + i * 14 + j;
            float dot = 0.f;
            #pragma unroll
            for (int c4 = 0; c4 < 8; ++c4) {
                float4 qv = *(const float4*)&stq[sp * QSTR + c4 * 4];
                dot += kc[c4 * 4 + 0] * qv.x + kc[c4 * 4 + 1] * qv.y
                     + kc[c4 * 4 + 2] * qv.z + kc[c4 * 4 + 3] * qv.w;
            }
            float lv = rhw[i][lane] + rhw[7 + j][lane] + dot;
            l[c] = lv;
            lm = fmaxf(lm, lv);
        } else {
            l[c] = -1e30f;
        }
    }
    mpart[w][lane] = lm;
    __syncthreads();

    float m = mpart[0][lane];
    #pragma unroll
    for (int ww = 1; ww < NW; ++ww) m = fmaxf(m, mpart[ww][lane]);

    float lsum = 0.f;
    #pragma unroll
    for (int c = 0; c < 7; ++c) {
        const int k = w + c * NW;
        if (k < KK) {
            float e = __expf(l[c] - m);
            lsum += e;
            Llds[k][lane] = (unsigned short)f2bf(e);
        }
    }
    spart[w][lane] = lsum;
    __syncthreads();

    float s = spart[0][lane];
    #pragma unroll
    for (int ww = 1; ww < NW; ++ww) s += spart[ww][lane];
    const float inv = 1.f / s;

    // ---- PV: wave w owns d = 4w..4w+3 ----
    const int d0 = w * 4;
    float o0 = 0.f, o1 = 0.f, o2 = 0.f, o3 = 0.f;
    #pragma unroll
    for (int k = 0; k < KK; ++k) {
        const int i = k / 7, j = k - i * 7;       // compile-time constants
        int sp = spc + i * 14 + j;
        float e = bfb2f((unsigned)Llds[k][lane]);
        uint2 vv = *(const uint2*)&stv[sp * VSTR + d0];
        o0 += e * bf2f_lo(vv.x);
        o1 += e * bf2f_hi(vv.x);
        o2 += e * bf2f_lo(vv.y);
        o3 += e * bf2f_hi(vv.y);
    }
    const size_t ob = ((size_t)(b * NH + n) * HD + d0) * HW + pix;
    out[ob]          = o0 * inv;
    out[ob + HW]     = o1 * inv;
    out[ob + 2 * HW] = o2 * inv;
    out[ob + 3 * HW] = o3 * inv;
}

extern "C" void kernel_launch(void* const* d_in, const int* in_sizes, int n_in,
                              void* d_out, int out_size, void* d_ws, size_t ws_size,
                              hipStream_t stream) {
    const float* x     = (const float*)d_in[0];
    const float* Wk    = (const float*)d_in[1];
    const float* Wq    = (const float*)d_in[2];
    const float* Wv    = (const float*)d_in[3];
    const float* rel_h = (const float*)d_in[4];
    const float* rel_w = (const float*)d_in[5];
    float* out = (float*)d_out;
    float* ws  = (float*)d_ws;

    hipLaunchKernelGGL(proj_kernel, dim3(98, 12), dim3(256), 0, stream,
                       x, Wk, Wq, Wv, ws);
    hipLaunchKernelGGL(attn_kernel, dim3(784), dim3(512), 0, stream,
                       ws, rel_h, rel_w, out);
}